// Round 4
// baseline (743.678 us; speedup 1.0000x reference)
//
#include <hip/hip_runtime.h>
#include <hip/hip_bf16.h>

#define N_EDGES 800000
#define M_BLK   64
#define TILES   4
#define EPB     (M_BLK * TILES)      // 256 edges per block
#define NBLK    (N_EDGES / EPB)      // 3125

typedef __attribute__((ext_vector_type(8))) _Float16 half8;
typedef __attribute__((ext_vector_type(4))) float    f32x4;

// ---------------- weight prep: transpose + fp32->fp16 ----------------
// ws layout (bytes):
//   0       wt1s  [128][192] f16   (49152)
//   49152   wt1v  [128][192] f16   (49152)
//   98304   wt2s  [64][128]  f16   (16384)
//   114688  wt2v  [32][128]  f16   (8192)
//   122880  w1s192[128] f32        (512)
//   123392  w1v192[128] f32        (512)
__global__ void prep_kernel(const float* __restrict__ W1s, const float* __restrict__ W1v,
                            const float* __restrict__ W2s, const float* __restrict__ W2v,
                            _Float16* __restrict__ wt1s, _Float16* __restrict__ wt1v,
                            _Float16* __restrict__ wt2s, _Float16* __restrict__ wt2v,
                            float* __restrict__ w1s192, float* __restrict__ w1v192)
{
    int idx = blockIdx.x * blockDim.x + threadIdx.x;
    if (idx < 128 * 192) {
        int c = idx / 192, k = idx % 192;
        wt1s[idx] = (_Float16)W1s[k * 128 + c];
        wt1v[idx] = (_Float16)W1v[k * 128 + c];
        return;
    }
    int i2 = idx - 128 * 192;
    if (i2 >= 0 && i2 < 64 * 128) {
        int c = i2 / 128, k = i2 % 128;
        wt2s[i2] = (_Float16)W2s[k * 64 + c];
        return;
    }
    int i3 = idx - (128 * 192 + 64 * 128);
    if (i3 >= 0 && i3 < 32 * 128) {
        int c = i3 / 128, k = i3 % 128;
        wt2v[i3] = (_Float16)W2v[k * 32 + c];
        return;
    }
    int i4 = idx - (128 * 192 + 64 * 128 + 32 * 128);
    if (i4 >= 0 && i4 < 128) {
        w1s192[i4] = W1s[192 * 128 + i4];
        w1v192[i4] = W1v[192 * 128 + i4];
    }
}

// XOR-swizzled LDS address: 16B chunk index ^= (row & 7). Conflict-free for
// both the stage writes and the MFMA fragment reads (row strides 384B/256B
// are 0 mod 128B, so unswizzled rows alias banks). Proven in R2.
__device__ __forceinline__ void* xsw(char* base, int row, int byte_in_row, int row_bytes)
{
    int chunk = byte_in_row >> 4;
    int sw    = ((chunk ^ (row & 7)) << 4) | (byte_in_row & 15);
    return (void*)(base + row * row_bytes + sw);
}

// ---------------- fused edge-MLP kernel ----------------
// 512 threads (8 waves), TILES=4 tiles of 64 edges.
// R3 lesson: gfx950 splits the 128-reg budget ~64 arch / 64 acc; asm-pinned
// persistent weights (48 arch regs) forced loop-carried spills (~1.4 GB HBM
// scratch traffic). R4: SEQUENTIAL stripe processing — scalar MLP fully, then
// vector MLP, reloading 6 W1 fragments (24 regs) from L2 per pass. Peak arch
// demand ~60 regs -> no spill; acc regs reused between passes.
__global__ __launch_bounds__(512, 4) void edge_mlp_kernel(
    const int*   __restrict__ endpoints,
    const float* __restrict__ edge_len,
    const float* __restrict__ theta,
    const float* __restrict__ feat,
    const float* __restrict__ b1s, const float* __restrict__ b2s,
    const float* __restrict__ b1v, const float* __restrict__ b2v,
    const _Float16* __restrict__ wt1s, const _Float16* __restrict__ wt1v,
    const _Float16* __restrict__ wt2s, const _Float16* __restrict__ wt2v,
    const float* __restrict__ w1s192, const float* __restrict__ w1v192,
    float* __restrict__ h0, float* __restrict__ v0)
{
    __shared__ char   ldsX [M_BLK * 384];   // X  [64] x 384B, swizzled
    __shared__ char   ldsHs[M_BLK * 256];   // Hs [64] x 256B, swizzled
    __shared__ char   ldsHv[M_BLK * 256];   // Hv [64] x 256B, swizzled
    __shared__ float  Len[M_BLK];
    __shared__ float2 Dir[M_BLK];

    const int t   = threadIdx.x;
    const int blk = blockIdx.x;
    const int w   = t >> 6;
    const int l   = t & 63;
    const int lr  = l & 15;
    const int lk  = l >> 4;
    const int e   = t >> 3;         // edge within tile (0..63)
    const int f0q = t & 7;          // 16B feature chunk (0..7)
    const int base = blk * EPB;

    const int c1 = w * 16 + lr;     // layer-1 hidden column owned by this lane
    const float b1s_c   = b1s[c1];
    const float b1v_c   = b1v[c1];
    const float w192s_c = w1s192[c1];
    const float w192v_c = w1v192[c1];

    const int rt2 = w >> 1;
    const int ch  = w & 1;
    const float b2s_a = b2s[ch * 32 + lr];
    const float b2s_b = b2s[ch * 32 + 16 + lr];
    const float b2v_c = b2v[ch * 16 + lr];

    // per-lane W1 fragment base byte offsets (stripe col c1, k-group lk)
    const char* pws_base = (const char*)wt1s + c1 * 384 + lk * 16;
    const char* pwv_base = (const char*)wt1v + c1 * 384 + lk * 16;

    // ---- prologue prefetch: tile 0 feat + len/theta; endpoints tiles 1,2 ----
    float4 fi0, fi1, fj0, fj1;
    float  len_pf = 0.f, th_pf = 0.f;
    {
        int2 ep0 = ((const int2*)endpoints)[base + e];
        const float* pfi = feat + (size_t)ep0.x * 64 + f0q * 8;
        const float* pfj = feat + (size_t)ep0.y * 64 + f0q * 8;
        fi0 = ((const float4*)pfi)[0]; fi1 = ((const float4*)pfi)[1];
        fj0 = ((const float4*)pfj)[0]; fj1 = ((const float4*)pfj)[1];
        if (t < M_BLK)          len_pf = edge_len[base + t];
        else if (t < 2 * M_BLK) th_pf  = theta[base + (t - M_BLK)];
    }
    int2 epA = ((const int2*)endpoints)[base + 1 * M_BLK + e];
    int2 epB = ((const int2*)endpoints)[base + 2 * M_BLK + e];

    for (int tile = 0; tile < TILES; ++tile) {
        // ---- PH0: convert prefetched gather -> LDS X, Len, Dir ----
        {
            float ai[8] = {fi0.x, fi0.y, fi0.z, fi0.w, fi1.x, fi1.y, fi1.z, fi1.w};
            float bj[8] = {fj0.x, fj0.y, fj0.z, fj0.w, fj1.x, fj1.y, fj1.z, fj1.w};
            half8 pi, pj, pd;
#pragma unroll
            for (int q = 0; q < 8; ++q) {
                pi[q] = (_Float16)ai[q];
                pj[q] = (_Float16)bj[q];
                pd[q] = (_Float16)fabsf(ai[q] - bj[q]);
            }
            *(half8*)xsw(ldsX, e, f0q * 16, 384)       = pi;
            *(half8*)xsw(ldsX, e, 128 + f0q * 16, 384) = pj;
            *(half8*)xsw(ldsX, e, 256 + f0q * 16, 384) = pd;
            if (t < M_BLK)          Len[t] = len_pf;
            else if (t < 2 * M_BLK) Dir[t - M_BLK] = make_float2(cosf(th_pf), sinf(th_pf));
        }
        __syncthreads();   // A: X/Len/Dir visible to all

        // ---- issue next-tile gather prefetch (drains under the MFMA work) ----
        if (tile + 1 < TILES) {
            const float* pfi = feat + (size_t)epA.x * 64 + f0q * 8;
            const float* pfj = feat + (size_t)epA.y * 64 + f0q * 8;
            fi0 = ((const float4*)pfi)[0]; fi1 = ((const float4*)pfi)[1];
            fj0 = ((const float4*)pfj)[0]; fj1 = ((const float4*)pfj)[1];
            if (t < M_BLK)          len_pf = edge_len[base + (tile + 1) * M_BLK + t];
            else if (t < 2 * M_BLK) th_pf  = theta[base + (tile + 1) * M_BLK + (t - M_BLK)];
        }
        epA = epB;
        if (tile + 3 < TILES)
            epB = ((const int2*)endpoints)[base + (tile + 3) * M_BLK + e];

        // ---- PH1a: scalar-MLP layer 1 (weights live briefly: 24 arch regs) ----
        {
            half8 bw[6];
#pragma unroll
            for (int ks = 0; ks < 6; ++ks)
                bw[ks] = *reinterpret_cast<const half8*>(pws_base + ks * 64);
            f32x4 acc[4];
#pragma unroll
            for (int rt = 0; rt < 4; ++rt) acc[rt] = (f32x4){0.f, 0.f, 0.f, 0.f};
#pragma unroll
            for (int rt = 0; rt < 4; ++rt)
#pragma unroll
                for (int ks = 0; ks < 6; ++ks) {
                    half8 a = *(half8*)xsw(ldsX, rt * 16 + lr, ks * 64 + lk * 16, 384);
                    acc[rt] = __builtin_amdgcn_mfma_f32_16x16x32_f16(a, bw[ks], acc[rt], 0, 0, 0);
                }
#pragma unroll
            for (int rt = 0; rt < 4; ++rt)
#pragma unroll
                for (int r = 0; r < 4; ++r) {
                    int row = rt * 16 + lk * 4 + r;
                    float hs = acc[rt][r] + b1s_c + Len[row] * w192s_c;
                    *(_Float16*)xsw(ldsHs, row, c1 * 2, 256) = (_Float16)fmaxf(hs, 0.f);
                }
        }

        // ---- PH1b: vector-MLP layer 1 (same registers reused) ----
        {
            half8 bw[6];
#pragma unroll
            for (int ks = 0; ks < 6; ++ks)
                bw[ks] = *reinterpret_cast<const half8*>(pwv_base + ks * 64);
            f32x4 acc[4];
#pragma unroll
            for (int rt = 0; rt < 4; ++rt) acc[rt] = (f32x4){0.f, 0.f, 0.f, 0.f};
#pragma unroll
            for (int rt = 0; rt < 4; ++rt)
#pragma unroll
                for (int ks = 0; ks < 6; ++ks) {
                    half8 a = *(half8*)xsw(ldsX, rt * 16 + lr, ks * 64 + lk * 16, 384);
                    acc[rt] = __builtin_amdgcn_mfma_f32_16x16x32_f16(a, bw[ks], acc[rt], 0, 0, 0);
                }
#pragma unroll
            for (int rt = 0; rt < 4; ++rt)
#pragma unroll
                for (int r = 0; r < 4; ++r) {
                    int row = rt * 16 + lk * 4 + r;
                    float hv = acc[rt][r] + b1v_c + Len[row] * w192v_c;
                    *(_Float16*)xsw(ldsHv, row, c1 * 2, 256) = (_Float16)fmaxf(hv, 0.f);
                }
        }
        __syncthreads();   // B: Hs/Hv visible to all

        // ---- PH3: layer 2 + global stores ----
        {
            f32x4 acc2[2];
            acc2[0] = (f32x4){0.f, 0.f, 0.f, 0.f};
            acc2[1] = (f32x4){0.f, 0.f, 0.f, 0.f};
            f32x4 accV = (f32x4){0.f, 0.f, 0.f, 0.f};
            const int cv = ch * 16 + lr;
#pragma unroll
            for (int ks = 0; ks < 4; ++ks) {
                half8 a2 = *(half8*)xsw(ldsHs, rt2 * 16 + lr, ks * 64 + lk * 16, 256);
#pragma unroll
                for (int ct = 0; ct < 2; ++ct) {
                    int c2 = ch * 32 + ct * 16 + lr;
                    half8 b = *reinterpret_cast<const half8*>(wt2s + c2 * 128 + ks * 32 + lk * 8);
                    acc2[ct] = __builtin_amdgcn_mfma_f32_16x16x32_f16(a2, b, acc2[ct], 0, 0, 0);
                }
                half8 av  = *(half8*)xsw(ldsHv, rt2 * 16 + lr, ks * 64 + lk * 16, 256);
                half8 bv2 = *reinterpret_cast<const half8*>(wt2v + cv * 128 + ks * 32 + lk * 8);
                accV = __builtin_amdgcn_mfma_f32_16x16x32_f16(av, bv2, accV, 0, 0, 0);
            }
            const size_t grow0 = (size_t)(base + tile * M_BLK);
#pragma unroll
            for (int ct = 0; ct < 2; ++ct) {
                int c2 = ch * 32 + ct * 16 + lr;
                float bias = ct ? b2s_b : b2s_a;
#pragma unroll
                for (int r = 0; r < 4; ++r) {
                    int row = rt2 * 16 + lk * 4 + r;
                    h0[(grow0 + row) * 64 + c2] = acc2[ct][r] + bias;
                }
            }
#pragma unroll
            for (int r = 0; r < 4; ++r) {
                int row = rt2 * 16 + lk * 4 + r;
                float amp = accV[r] + b2v_c;
                float2 d = Dir[row];
                *reinterpret_cast<float2*>(v0 + ((grow0 + row) * 32 + cv) * 2) =
                    make_float2(amp * d.x, amp * d.y);
            }
        }
        __syncthreads();   // C: PH3 H/Dir reads done before next PH0 writes
    }
}

extern "C" void kernel_launch(void* const* d_in, const int* in_sizes, int n_in,
                              void* d_out, int out_size, void* d_ws, size_t ws_size,
                              hipStream_t stream)
{
    const int*   endpoints = (const int*)d_in[0];
    const float* edge_len  = (const float*)d_in[1];
    const float* theta     = (const float*)d_in[2];
    const float* feat      = (const float*)d_in[3];
    const float* W1s       = (const float*)d_in[4];
    const float* b1s       = (const float*)d_in[5];
    const float* W2s       = (const float*)d_in[6];
    const float* b2s       = (const float*)d_in[7];
    const float* W1v       = (const float*)d_in[8];
    const float* b1v       = (const float*)d_in[9];
    const float* W2v       = (const float*)d_in[10];
    const float* b2v       = (const float*)d_in[11];

    char* ws = (char*)d_ws;
    _Float16* wt1s   = (_Float16*)(ws);
    _Float16* wt1v   = (_Float16*)(ws + 49152);
    _Float16* wt2s   = (_Float16*)(ws + 98304);
    _Float16* wt2v   = (_Float16*)(ws + 114688);
    float*    w1s192 = (float*)(ws + 122880);
    float*    w1v192 = (float*)(ws + 123392);

    prep_kernel<<<145, 256, 0, stream>>>(W1s, W1v, W2s, W2v,
                                         wt1s, wt1v, wt2s, wt2v, w1s192, w1v192);

    float* h0 = (float*)d_out;
    float* v0 = h0 + (size_t)N_EDGES * 64;
    edge_mlp_kernel<<<NBLK, 512, 0, stream>>>(endpoints, edge_len, theta, feat,
                                              b1s, b2s, b1v, b2v,
                                              wt1s, wt1v, wt2s, wt2v,
                                              w1s192, w1v192, h0, v0);
}

// Round 5
// 740.704 us; speedup vs baseline: 1.0040x; 1.0040x over previous
//
#include <hip/hip_runtime.h>
#include <hip/hip_bf16.h>

#define N_EDGES 800000
#define M_BLK   64
#define TILES   4
#define EPB     (M_BLK * TILES)      // 256 edges per block
#define NBLK    (N_EDGES / EPB)      // 3125

typedef __attribute__((ext_vector_type(8))) _Float16 half8;
typedef __attribute__((ext_vector_type(4))) float    f32x4;

// ---------------- weight prep: transpose + fp32->fp16 ----------------
// ws layout (bytes):
//   0       wt1s  [128][192] f16   (49152)
//   49152   wt1v  [128][192] f16   (49152)
//   98304   wt2s  [64][128]  f16   (16384)
//   114688  wt2v  [32][128]  f16   (8192)
//   122880  w1s192[128] f32        (512)
//   123392  w1v192[128] f32        (512)
__global__ void prep_kernel(const float* __restrict__ W1s, const float* __restrict__ W1v,
                            const float* __restrict__ W2s, const float* __restrict__ W2v,
                            _Float16* __restrict__ wt1s, _Float16* __restrict__ wt1v,
                            _Float16* __restrict__ wt2s, _Float16* __restrict__ wt2v,
                            float* __restrict__ w1s192, float* __restrict__ w1v192)
{
    int idx = blockIdx.x * blockDim.x + threadIdx.x;
    if (idx < 128 * 192) {
        int c = idx / 192, k = idx % 192;
        wt1s[idx] = (_Float16)W1s[k * 128 + c];
        wt1v[idx] = (_Float16)W1v[k * 128 + c];
        return;
    }
    int i2 = idx - 128 * 192;
    if (i2 >= 0 && i2 < 64 * 128) {
        int c = i2 / 128, k = i2 % 128;
        wt2s[i2] = (_Float16)W2s[k * 64 + c];
        return;
    }
    int i3 = idx - (128 * 192 + 64 * 128);
    if (i3 >= 0 && i3 < 32 * 128) {
        int c = i3 / 128, k = i3 % 128;
        wt2v[i3] = (_Float16)W2v[k * 32 + c];
        return;
    }
    int i4 = idx - (128 * 192 + 64 * 128 + 32 * 128);
    if (i4 >= 0 && i4 < 128) {
        w1s192[i4] = W1s[192 * 128 + i4];
        w1v192[i4] = W1v[192 * 128 + i4];
    }
}

// XOR-swizzled LDS address: 16B chunk index ^= (row & 7). Conflict-free for
// both the stage writes and the MFMA fragment reads (row strides 384B/256B
// are 0 mod 128B, so unswizzled rows alias banks). Proven in R2.
__device__ __forceinline__ void* xsw(char* base, int row, int byte_in_row, int row_bytes)
{
    int chunk = byte_in_row >> 4;
    int sw    = ((chunk ^ (row & 7)) << 4) | (byte_in_row & 15);
    return (void*)(base + row * row_bytes + sw);
}

// ---------------- fused edge-MLP kernel ----------------
// 512 threads (8 waves), TILES=4 tiles of 64 edges.
// Register-cap history: R2 bounds(512,6) and R3/R4 bounds(512,4) both pinned
// the arch half at 40/64 regs -> loop-carried prefetch spilled to scratch
// (~1.5 GB HBM traffic). R1 with NO bounds had zero spill. Occupancy is
// LDS-bound (58 KB -> 2 blocks/CU) so a free allocator costs nothing.
// => NO __launch_bounds__. Sequential stripe passes keep transient weight
// demand at 24 regs (prevents R1's 48-reg sink pathology).
__global__ void edge_mlp_kernel(
    const int*   __restrict__ endpoints,
    const float* __restrict__ edge_len,
    const float* __restrict__ theta,
    const float* __restrict__ feat,
    const float* __restrict__ b1s, const float* __restrict__ b2s,
    const float* __restrict__ b1v, const float* __restrict__ b2v,
    const _Float16* __restrict__ wt1s, const _Float16* __restrict__ wt1v,
    const _Float16* __restrict__ wt2s, const _Float16* __restrict__ wt2v,
    const float* __restrict__ w1s192, const float* __restrict__ w1v192,
    float* __restrict__ h0, float* __restrict__ v0)
{
    __shared__ char   ldsX [M_BLK * 384];   // X  [64] x 384B, swizzled
    __shared__ char   ldsHs[M_BLK * 256];   // Hs [64] x 256B, swizzled
    __shared__ char   ldsHv[M_BLK * 256];   // Hv [64] x 256B, swizzled
    __shared__ float  Len[M_BLK];
    __shared__ float2 Dir[M_BLK];

    const int t   = threadIdx.x;
    const int blk = blockIdx.x;
    const int w   = t >> 6;
    const int l   = t & 63;
    const int lr  = l & 15;
    const int lk  = l >> 4;
    const int e   = t >> 3;         // edge within tile (0..63)
    const int f0q = t & 7;          // 16B feature chunk (0..7)
    const int base = blk * EPB;

    const int c1 = w * 16 + lr;     // layer-1 hidden column owned by this lane
    const float b1s_c   = b1s[c1];
    const float b1v_c   = b1v[c1];
    const float w192s_c = w1s192[c1];
    const float w192v_c = w1v192[c1];

    const int rt2 = w >> 1;
    const int ch  = w & 1;
    const float b2s_a = b2s[ch * 32 + lr];
    const float b2s_b = b2s[ch * 32 + 16 + lr];
    const float b2v_c = b2v[ch * 16 + lr];

    // ---- prologue prefetch: tile 0 feat + len/theta; endpoints tiles 1,2 ----
    float4 fi0, fi1, fj0, fj1;
    float  len_pf = 0.f, th_pf = 0.f;
    {
        int2 ep0 = ((const int2*)endpoints)[base + e];
        const float* pfi = feat + (size_t)ep0.x * 64 + f0q * 8;
        const float* pfj = feat + (size_t)ep0.y * 64 + f0q * 8;
        fi0 = ((const float4*)pfi)[0]; fi1 = ((const float4*)pfi)[1];
        fj0 = ((const float4*)pfj)[0]; fj1 = ((const float4*)pfj)[1];
        if (t < M_BLK)          len_pf = edge_len[base + t];
        else if (t < 2 * M_BLK) th_pf  = theta[base + (t - M_BLK)];
    }
    int2 epA = ((const int2*)endpoints)[base + 1 * M_BLK + e];
    int2 epB = ((const int2*)endpoints)[base + 2 * M_BLK + e];

    for (int tile = 0; tile < TILES; ++tile) {
        // ---- PH0: convert prefetched gather -> LDS X, Len, Dir ----
        {
            float ai[8] = {fi0.x, fi0.y, fi0.z, fi0.w, fi1.x, fi1.y, fi1.z, fi1.w};
            float bj[8] = {fj0.x, fj0.y, fj0.z, fj0.w, fj1.x, fj1.y, fj1.z, fj1.w};
            half8 pi, pj, pd;
#pragma unroll
            for (int q = 0; q < 8; ++q) {
                pi[q] = (_Float16)ai[q];
                pj[q] = (_Float16)bj[q];
                pd[q] = (_Float16)fabsf(ai[q] - bj[q]);
            }
            *(half8*)xsw(ldsX, e, f0q * 16, 384)       = pi;
            *(half8*)xsw(ldsX, e, 128 + f0q * 16, 384) = pj;
            *(half8*)xsw(ldsX, e, 256 + f0q * 16, 384) = pd;
            if (t < M_BLK)          Len[t] = len_pf;
            else if (t < 2 * M_BLK) Dir[t - M_BLK] = make_float2(cosf(th_pf), sinf(th_pf));
        }
        __syncthreads();   // A: X/Len/Dir visible to all

        // ---- issue next-tile gather prefetch (drains under the MFMA work) ----
        if (tile + 1 < TILES) {
            const float* pfi = feat + (size_t)epA.x * 64 + f0q * 8;
            const float* pfj = feat + (size_t)epA.y * 64 + f0q * 8;
            fi0 = ((const float4*)pfi)[0]; fi1 = ((const float4*)pfi)[1];
            fj0 = ((const float4*)pfj)[0]; fj1 = ((const float4*)pfj)[1];
            if (t < M_BLK)          len_pf = edge_len[base + (tile + 1) * M_BLK + t];
            else if (t < 2 * M_BLK) th_pf  = theta[base + (tile + 1) * M_BLK + (t - M_BLK)];
        }
        epA = epB;
        if (tile + 3 < TILES)
            epB = ((const int2*)endpoints)[base + (tile + 3) * M_BLK + e];

        // ---- PH1a: scalar-MLP layer 1 (weights live briefly: 24 arch regs) ----
        {
            const char* pws = (const char*)wt1s + c1 * 384 + lk * 16;
            half8 bw[6];
#pragma unroll
            for (int ks = 0; ks < 6; ++ks)
                bw[ks] = *reinterpret_cast<const half8*>(pws + ks * 64);
            f32x4 acc[4];
#pragma unroll
            for (int rt = 0; rt < 4; ++rt) acc[rt] = (f32x4){0.f, 0.f, 0.f, 0.f};
#pragma unroll
            for (int rt = 0; rt < 4; ++rt)
#pragma unroll
                for (int ks = 0; ks < 6; ++ks) {
                    half8 a = *(half8*)xsw(ldsX, rt * 16 + lr, ks * 64 + lk * 16, 384);
                    acc[rt] = __builtin_amdgcn_mfma_f32_16x16x32_f16(a, bw[ks], acc[rt], 0, 0, 0);
                }
#pragma unroll
            for (int rt = 0; rt < 4; ++rt)
#pragma unroll
                for (int r = 0; r < 4; ++r) {
                    int row = rt * 16 + lk * 4 + r;
                    float hs = acc[rt][r] + b1s_c + Len[row] * w192s_c;
                    *(_Float16*)xsw(ldsHs, row, c1 * 2, 256) = (_Float16)fmaxf(hs, 0.f);
                }
        }

        // ---- PH1b: vector-MLP layer 1 (same registers reused) ----
        {
            const char* pwv = (const char*)wt1v + c1 * 384 + lk * 16;
            half8 bw[6];
#pragma unroll
            for (int ks = 0; ks < 6; ++ks)
                bw[ks] = *reinterpret_cast<const half8*>(pwv + ks * 64);
            f32x4 acc[4];
#pragma unroll
            for (int rt = 0; rt < 4; ++rt) acc[rt] = (f32x4){0.f, 0.f, 0.f, 0.f};
#pragma unroll
            for (int rt = 0; rt < 4; ++rt)
#pragma unroll
                for (int ks = 0; ks < 6; ++ks) {
                    half8 a = *(half8*)xsw(ldsX, rt * 16 + lr, ks * 64 + lk * 16, 384);
                    acc[rt] = __builtin_amdgcn_mfma_f32_16x16x32_f16(a, bw[ks], acc[rt], 0, 0, 0);
                }
#pragma unroll
            for (int rt = 0; rt < 4; ++rt)
#pragma unroll
                for (int r = 0; r < 4; ++r) {
                    int row = rt * 16 + lk * 4 + r;
                    float hv = acc[rt][r] + b1v_c + Len[row] * w192v_c;
                    *(_Float16*)xsw(ldsHv, row, c1 * 2, 256) = (_Float16)fmaxf(hv, 0.f);
                }
        }
        __syncthreads();   // B: Hs/Hv visible to all

        // ---- PH3: layer 2 + global stores ----
        {
            f32x4 acc2[2];
            acc2[0] = (f32x4){0.f, 0.f, 0.f, 0.f};
            acc2[1] = (f32x4){0.f, 0.f, 0.f, 0.f};
            f32x4 accV = (f32x4){0.f, 0.f, 0.f, 0.f};
            const int cv = ch * 16 + lr;
#pragma unroll
            for (int ks = 0; ks < 4; ++ks) {
                half8 a2 = *(half8*)xsw(ldsHs, rt2 * 16 + lr, ks * 64 + lk * 16, 256);
#pragma unroll
                for (int ct = 0; ct < 2; ++ct) {
                    int c2 = ch * 32 + ct * 16 + lr;
                    half8 b = *reinterpret_cast<const half8*>(wt2s + c2 * 128 + ks * 32 + lk * 8);
                    acc2[ct] = __builtin_amdgcn_mfma_f32_16x16x32_f16(a2, b, acc2[ct], 0, 0, 0);
                }
                half8 av  = *(half8*)xsw(ldsHv, rt2 * 16 + lr, ks * 64 + lk * 16, 256);
                half8 bv2 = *reinterpret_cast<const half8*>(wt2v + cv * 128 + ks * 32 + lk * 8);
                accV = __builtin_amdgcn_mfma_f32_16x16x32_f16(av, bv2, accV, 0, 0, 0);
            }
            const size_t grow0 = (size_t)(base + tile * M_BLK);
#pragma unroll
            for (int ct = 0; ct < 2; ++ct) {
                int c2 = ch * 32 + ct * 16 + lr;
                float bias = ct ? b2s_b : b2s_a;
#pragma unroll
                for (int r = 0; r < 4; ++r) {
                    int row = rt2 * 16 + lk * 4 + r;
                    h0[(grow0 + row) * 64 + c2] = acc2[ct][r] + bias;
                }
            }
#pragma unroll
            for (int r = 0; r < 4; ++r) {
                int row = rt2 * 16 + lk * 4 + r;
                float amp = accV[r] + b2v_c;
                float2 d = Dir[row];
                *reinterpret_cast<float2*>(v0 + ((grow0 + row) * 32 + cv) * 2) =
                    make_float2(amp * d.x, amp * d.y);
            }
        }
        __syncthreads();   // C: PH3 H/Dir reads done before next PH0 writes
    }
}

extern "C" void kernel_launch(void* const* d_in, const int* in_sizes, int n_in,
                              void* d_out, int out_size, void* d_ws, size_t ws_size,
                              hipStream_t stream)
{
    const int*   endpoints = (const int*)d_in[0];
    const float* edge_len  = (const float*)d_in[1];
    const float* theta     = (const float*)d_in[2];
    const float* feat      = (const float*)d_in[3];
    const float* W1s       = (const float*)d_in[4];
    const float* b1s       = (const float*)d_in[5];
    const float* W2s       = (const float*)d_in[6];
    const float* b2s       = (const float*)d_in[7];
    const float* W1v       = (const float*)d_in[8];
    const float* b1v       = (const float*)d_in[9];
    const float* W2v       = (const float*)d_in[10];
    const float* b2v       = (const float*)d_in[11];

    char* ws = (char*)d_ws;
    _Float16* wt1s   = (_Float16*)(ws);
    _Float16* wt1v   = (_Float16*)(ws + 49152);
    _Float16* wt2s   = (_Float16*)(ws + 98304);
    _Float16* wt2v   = (_Float16*)(ws + 114688);
    float*    w1s192 = (float*)(ws + 122880);
    float*    w1v192 = (float*)(ws + 123392);

    prep_kernel<<<145, 256, 0, stream>>>(W1s, W1v, W2s, W2v,
                                         wt1s, wt1v, wt2s, wt2v, w1s192, w1v192);

    float* h0 = (float*)d_out;
    float* v0 = h0 + (size_t)N_EDGES * 64;
    edge_mlp_kernel<<<NBLK, 512, 0, stream>>>(endpoints, edge_len, theta, feat,
                                              b1s, b2s, b1v, b2v,
                                              wt1s, wt1v, wt2s, wt2v,
                                              w1s192, w1v192, h0, v0);
}

// Round 6
// 329.811 us; speedup vs baseline: 2.2549x; 2.2458x over previous
//
#include <hip/hip_runtime.h>
#include <hip/hip_bf16.h>

#define N_EDGES 800000
#define M_BLK   64
#define NBLK    (N_EDGES / M_BLK)   // 12500

typedef __attribute__((ext_vector_type(8))) _Float16 half8;
typedef __attribute__((ext_vector_type(4))) float    f32x4;

// ---------------- weight prep: transpose + fp32->fp16 ----------------
// ws layout (bytes):
//   0       wt1s  [128][192] f16   (49152)
//   49152   wt1v  [128][192] f16   (49152)
//   98304   wt2s  [64][128]  f16   (16384)
//   114688  wt2v  [32][128]  f16   (8192)
//   122880  w1s192[128] f32        (512)
//   123392  w1v192[128] f32        (512)
__global__ void prep_kernel(const float* __restrict__ W1s, const float* __restrict__ W1v,
                            const float* __restrict__ W2s, const float* __restrict__ W2v,
                            _Float16* __restrict__ wt1s, _Float16* __restrict__ wt1v,
                            _Float16* __restrict__ wt2s, _Float16* __restrict__ wt2v,
                            float* __restrict__ w1s192, float* __restrict__ w1v192)
{
    int idx = blockIdx.x * blockDim.x + threadIdx.x;
    if (idx < 128 * 192) {
        int c = idx / 192, k = idx % 192;
        wt1s[idx] = (_Float16)W1s[k * 128 + c];
        wt1v[idx] = (_Float16)W1v[k * 128 + c];
        return;
    }
    int i2 = idx - 128 * 192;
    if (i2 >= 0 && i2 < 64 * 128) {
        int c = i2 / 128, k = i2 % 128;
        wt2s[i2] = (_Float16)W2s[k * 64 + c];
        return;
    }
    int i3 = idx - (128 * 192 + 64 * 128);
    if (i3 >= 0 && i3 < 32 * 128) {
        int c = i3 / 128, k = i3 % 128;
        wt2v[i3] = (_Float16)W2v[k * 32 + c];
        return;
    }
    int i4 = idx - (128 * 192 + 64 * 128 + 32 * 128);
    if (i4 >= 0 && i4 < 128) {
        w1s192[i4] = W1s[192 * 128 + i4];
        w1v192[i4] = W1v[192 * 128 + i4];
    }
}

// XOR-swizzled LDS address: 16B chunk index ^= (row & 7). Conflict-free for
// both the stage writes and the MFMA fragment reads (row strides 384B/256B
// are 0 mod 128B, so unswizzled rows alias banks). Proven in R2.
__device__ __forceinline__ void* xsw(char* base, int row, int byte_in_row, int row_bytes)
{
    int chunk = byte_in_row >> 4;
    int sw    = ((chunk ^ (row & 7)) << 4) | (byte_in_row & 15);
    return (void*)(base + row * row_bytes + sw);
}

// ---------------- fused edge-MLP kernel ----------------
// One 64-edge tile per block (grid 12500), 512 threads / 8 waves.
// SPILL HISTORY: any tile-loop with loop-carried gather prefetch spills
// ~750MB to scratch regardless of __launch_bounds__ (R2-R5). The only
// no-spill shape was R1's loop-free block (WRITE_SIZE == output exactly).
// This keeps that shape and fixes R1's latency problems:
//  - sequential W-stripe passes with ks-outer depth-1 weight pipeline
//    (<=8 VGPRs of weights live -> nothing to sink/spill; R1 sank 48 regs
//    of weight loads into the MFMA loop, serializing L2 reloads)
//  - Hv aliases dead X region: LDS 41.7KB -> 3 blocks/CU (24 waves, 75%)
__global__ void edge_mlp_kernel(
    const int*   __restrict__ endpoints,
    const float* __restrict__ edge_len,
    const float* __restrict__ theta,
    const float* __restrict__ feat,
    const float* __restrict__ b1s, const float* __restrict__ b2s,
    const float* __restrict__ b1v, const float* __restrict__ b2v,
    const _Float16* __restrict__ wt1s, const _Float16* __restrict__ wt1v,
    const _Float16* __restrict__ wt2s, const _Float16* __restrict__ wt2v,
    const float* __restrict__ w1s192, const float* __restrict__ w1v192,
    float* __restrict__ h0, float* __restrict__ v0)
{
    __shared__ char   ldsX [M_BLK * 384];   // X [64]x384B swizzled; Hv aliases [0:16K) later
    __shared__ char   ldsHs[M_BLK * 256];   // Hs [64]x256B swizzled
    __shared__ float  Len[M_BLK];
    __shared__ float2 Dir[M_BLK];

    const int t   = threadIdx.x;
    const int blk = blockIdx.x;
    const int w   = t >> 6;
    const int l   = t & 63;
    const int lr  = l & 15;
    const int lk  = l >> 4;
    const int e   = t >> 3;         // edge within tile (0..63)
    const int f0q = t & 7;          // 16B feature chunk (0..7)
    const int base = blk * M_BLK;

    const int c1 = w * 16 + lr;     // layer-1 hidden column owned by this lane

    // ---- gather + convert -> LDS X, Len, Dir ----
    {
        int2 ep0 = ((const int2*)endpoints)[base + e];
        const float* pfi = feat + (size_t)ep0.x * 64 + f0q * 8;
        const float* pfj = feat + (size_t)ep0.y * 64 + f0q * 8;
        float4 fi0 = ((const float4*)pfi)[0], fi1 = ((const float4*)pfi)[1];
        float4 fj0 = ((const float4*)pfj)[0], fj1 = ((const float4*)pfj)[1];
        float ai[8] = {fi0.x, fi0.y, fi0.z, fi0.w, fi1.x, fi1.y, fi1.z, fi1.w};
        float bj[8] = {fj0.x, fj0.y, fj0.z, fj0.w, fj1.x, fj1.y, fj1.z, fj1.w};
        half8 pi, pj, pd;
#pragma unroll
        for (int q = 0; q < 8; ++q) {
            pi[q] = (_Float16)ai[q];
            pj[q] = (_Float16)bj[q];
            pd[q] = (_Float16)fabsf(ai[q] - bj[q]);
        }
        *(half8*)xsw(ldsX, e, f0q * 16, 384)       = pi;
        *(half8*)xsw(ldsX, e, 128 + f0q * 16, 384) = pj;
        *(half8*)xsw(ldsX, e, 256 + f0q * 16, 384) = pd;
        if (t < M_BLK)          Len[t] = edge_len[base + t];
        else if (t < 2 * M_BLK) {
            float th = theta[base + (t - M_BLK)];
            Dir[t - M_BLK] = make_float2(cosf(th), sinf(th));
        }
    }

    const float b1s_c   = b1s[c1];
    const float b1v_c   = b1v[c1];
    const float w192s_c = w1s192[c1];
    const float w192v_c = w1v192[c1];
    const int rt2 = w >> 1;
    const int ch  = w & 1;
    const float b2s_a = b2s[ch * 32 + lr];
    const float b2s_b = b2s[ch * 32 + 16 + lr];
    const float b2v_c = b2v[ch * 16 + lr];

    __syncthreads();   // A: X/Len/Dir visible

    // ---- PH1a: scalar-MLP layer 1 (ks-outer, depth-1 weight pipeline) ----
    {
        const char* pws = (const char*)wt1s + c1 * 384 + lk * 16;
        f32x4 acc[4];
#pragma unroll
        for (int rt = 0; rt < 4; ++rt) acc[rt] = (f32x4){0.f, 0.f, 0.f, 0.f};
        half8 bw = *reinterpret_cast<const half8*>(pws);
#pragma unroll
        for (int ks = 0; ks < 6; ++ks) {
            half8 bwn = bw;
            if (ks < 5) bwn = *reinterpret_cast<const half8*>(pws + (ks + 1) * 64);
#pragma unroll
            for (int rt = 0; rt < 4; ++rt) {
                half8 a = *(half8*)xsw(ldsX, rt * 16 + lr, ks * 64 + lk * 16, 384);
                acc[rt] = __builtin_amdgcn_mfma_f32_16x16x32_f16(a, bw, acc[rt], 0, 0, 0);
            }
            bw = bwn;
        }
#pragma unroll
        for (int rt = 0; rt < 4; ++rt)
#pragma unroll
            for (int r = 0; r < 4; ++r) {
                int row = rt * 16 + lk * 4 + r;
                float hs = acc[rt][r] + b1s_c + Len[row] * w192s_c;
                *(_Float16*)xsw(ldsHs, row, c1 * 2, 256) = (_Float16)fmaxf(hs, 0.f);
            }
    }

    // ---- PH1b: vector-MLP layer 1 MFMAs (reads X; acc held over barrier) ----
    f32x4 accv[4];
    {
        const char* pwv = (const char*)wt1v + c1 * 384 + lk * 16;
#pragma unroll
        for (int rt = 0; rt < 4; ++rt) accv[rt] = (f32x4){0.f, 0.f, 0.f, 0.f};
        half8 bw = *reinterpret_cast<const half8*>(pwv);
#pragma unroll
        for (int ks = 0; ks < 6; ++ks) {
            half8 bwn = bw;
            if (ks < 5) bwn = *reinterpret_cast<const half8*>(pwv + (ks + 1) * 64);
#pragma unroll
            for (int rt = 0; rt < 4; ++rt) {
                half8 a = *(half8*)xsw(ldsX, rt * 16 + lr, ks * 64 + lk * 16, 384);
                accv[rt] = __builtin_amdgcn_mfma_f32_16x16x32_f16(a, bw, accv[rt], 0, 0, 0);
            }
            bw = bwn;
        }
    }
    __syncthreads();   // B: all X reads + Hs writes complete

    // ---- PH1b epilogue: Hv onto dead X region ----
    char* ldsHv = ldsX;
#pragma unroll
    for (int rt = 0; rt < 4; ++rt)
#pragma unroll
        for (int r = 0; r < 4; ++r) {
            int row = rt * 16 + lk * 4 + r;
            float hv = accv[rt][r] + b1v_c + Len[row] * w192v_c;
            *(_Float16*)xsw(ldsHv, row, c1 * 2, 256) = (_Float16)fmaxf(hv, 0.f);
        }
    __syncthreads();   // C: Hv visible

    // ---- PH3: layer 2 + global stores ----
    {
        f32x4 acc2[2];
        acc2[0] = (f32x4){0.f, 0.f, 0.f, 0.f};
        acc2[1] = (f32x4){0.f, 0.f, 0.f, 0.f};
        f32x4 accV = (f32x4){0.f, 0.f, 0.f, 0.f};
        const int cv = ch * 16 + lr;
#pragma unroll
        for (int ks = 0; ks < 4; ++ks) {
            half8 a2 = *(half8*)xsw(ldsHs, rt2 * 16 + lr, ks * 64 + lk * 16, 256);
#pragma unroll
            for (int ct = 0; ct < 2; ++ct) {
                int c2 = ch * 32 + ct * 16 + lr;
                half8 b = *reinterpret_cast<const half8*>(wt2s + c2 * 128 + ks * 32 + lk * 8);
                acc2[ct] = __builtin_amdgcn_mfma_f32_16x16x32_f16(a2, b, acc2[ct], 0, 0, 0);
            }
            half8 av  = *(half8*)xsw(ldsHv, rt2 * 16 + lr, ks * 64 + lk * 16, 256);
            half8 bv2 = *reinterpret_cast<const half8*>(wt2v + cv * 128 + ks * 32 + lk * 8);
            accV = __builtin_amdgcn_mfma_f32_16x16x32_f16(av, bv2, accV, 0, 0, 0);
        }
#pragma unroll
        for (int ct = 0; ct < 2; ++ct) {
            int c2 = ch * 32 + ct * 16 + lr;
            float bias = ct ? b2s_b : b2s_a;
#pragma unroll
            for (int r = 0; r < 4; ++r) {
                int row = rt2 * 16 + lk * 4 + r;
                h0[(size_t)(base + row) * 64 + c2] = acc2[ct][r] + bias;
            }
        }
#pragma unroll
        for (int r = 0; r < 4; ++r) {
            int row = rt2 * 16 + lk * 4 + r;
            float amp = accV[r] + b2v_c;
            float2 d = Dir[row];
            *reinterpret_cast<float2*>(v0 + ((size_t)(base + row) * 32 + cv) * 2) =
                make_float2(amp * d.x, amp * d.y);
        }
    }
}

extern "C" void kernel_launch(void* const* d_in, const int* in_sizes, int n_in,
                              void* d_out, int out_size, void* d_ws, size_t ws_size,
                              hipStream_t stream)
{
    const int*   endpoints = (const int*)d_in[0];
    const float* edge_len  = (const float*)d_in[1];
    const float* theta     = (const float*)d_in[2];
    const float* feat      = (const float*)d_in[3];
    const float* W1s       = (const float*)d_in[4];
    const float* b1s       = (const float*)d_in[5];
    const float* W2s       = (const float*)d_in[6];
    const float* b2s       = (const float*)d_in[7];
    const float* W1v       = (const float*)d_in[8];
    const float* b1v       = (const float*)d_in[9];
    const float* W2v       = (const float*)d_in[10];
    const float* b2v       = (const float*)d_in[11];

    char* ws = (char*)d_ws;
    _Float16* wt1s   = (_Float16*)(ws);
    _Float16* wt1v   = (_Float16*)(ws + 49152);
    _Float16* wt2s   = (_Float16*)(ws + 98304);
    _Float16* wt2v   = (_Float16*)(ws + 114688);
    float*    w1s192 = (float*)(ws + 122880);
    float*    w1v192 = (float*)(ws + 123392);

    prep_kernel<<<145, 256, 0, stream>>>(W1s, W1v, W2s, W2v,
                                         wt1s, wt1v, wt2s, wt2v, w1s192, w1v192);

    float* h0 = (float*)d_out;
    float* v0 = h0 + (size_t)N_EDGES * 64;
    edge_mlp_kernel<<<NBLK, 512, 0, stream>>>(endpoints, edge_len, theta, feat,
                                              b1s, b2s, b1v, b2v,
                                              wt1s, wt1v, wt2s, wt2v,
                                              w1s192, w1v192, h0, v0);
}